// Round 1
// baseline (309.944 us; speedup 1.0000x reference)
//
#include <hip/hip_runtime.h>
#include <math.h>

// Problem constants (from reference: MB=8, SEQ=2048, EMBDIM=64, N_TOKENS=8192)
#define MB_     8
#define SEQ_    2048
#define EMB     64
#define NTOK    8192
#define NQ      (MB_ * SEQ_)      // 16384 queries

// Tiling
#define QT      64                // queries per block
#define CT      64                // codewords per LDS tile
#define CSPLIT  4                 // codeword splits across blocks
#define CPB     (NTOK / CSPLIT)   // codewords per block = 2048
#define TPB     256
#define LPAD    68                // pad 64 -> 68 floats: keeps 16B alignment per row, breaks pow2 bank stride

// ---------------------------------------------------------------------------
// Kernel 1: ||w_c||^2 for every codeword -> ws table
// ---------------------------------------------------------------------------
__global__ void ynorm_kernel(const float* __restrict__ W, float* __restrict__ ynorm) {
    int c = blockIdx.x * blockDim.x + threadIdx.x;
    if (c >= NTOK) return;
    const float4* w4 = (const float4*)(W + (size_t)c * EMB);
    float s = 0.f;
#pragma unroll
    for (int i = 0; i < EMB / 4; ++i) {
        float4 v = w4[i];
        s = fmaf(v.x, v.x, s);
        s = fmaf(v.y, v.y, s);
        s = fmaf(v.z, v.z, s);
        s = fmaf(v.w, v.w, s);
    }
    ynorm[c] = s;
}

// ---------------------------------------------------------------------------
// Kernel 2: main distance + partial argmin.
// Block: 256 threads = 16(tx: codeword) x 16(ty: query), each thread owns a
// 4q x 4c register tile. LDS tiles stored transposed [d][q] / [d][c] so the
// per-d fragment reads are contiguous float4 (ds_read_b128, broadcast-heavy,
// <=2-way bank aliasing which is free on gfx950).
// ---------------------------------------------------------------------------
__global__ __launch_bounds__(TPB, 2) void vq_argmin_kernel(
    const float* __restrict__ X, const float* __restrict__ W,
    const float* __restrict__ ynorm,
    float* __restrict__ pval, int* __restrict__ pidx)
{
    __shared__ float Lq[EMB][LPAD];   // [d][q]  query tile (transposed)
    __shared__ float Lc[EMB][LPAD];   // [d][c]  codeword tile (transposed)
    __shared__ float RedV[QT][17];
    __shared__ int   RedI[QT][17];

    const int t  = threadIdx.x;
    const int tx = t & 15;       // codeword group within tile
    const int ty = t >> 4;       // query group within tile
    const int tx4 = tx * 4;
    const int ty4 = ty * 4;

    const int qbase  = blockIdx.x * QT;        // 0..16320
    const int cbase0 = blockIdx.y * CPB;       // codeword split base

    // --- load query tile (transposed into LDS) ---
    {
        int qr = t >> 2;                 // 0..63 row within tile
        int d0 = (t & 3) * 16;           // 4 float4s along d
        const float4* src = (const float4*)(X + (size_t)(qbase + qr) * EMB + d0);
#pragma unroll
        for (int i = 0; i < 4; ++i) {
            float4 v = src[i];
            int d = d0 + i * 4;
            Lq[d + 0][qr] = v.x;
            Lq[d + 1][qr] = v.y;
            Lq[d + 2][qr] = v.z;
            Lq[d + 3][qr] = v.w;
        }
    }

    float minv[4] = {INFINITY, INFINITY, INFINITY, INFINITY};
    int   mini[4] = {0, 0, 0, 0};

    for (int ct = 0; ct < CPB; ct += CT) {
        const int cbase = cbase0 + ct;

        __syncthreads();   // protect Lc writes vs previous-iter reads; also publishes Lq on iter 0
        // --- load codeword tile (transposed into LDS) ---
        {
            int cr = t >> 2;
            int d0 = (t & 3) * 16;
            const float4* src = (const float4*)(W + (size_t)(cbase + cr) * EMB + d0);
#pragma unroll
            for (int i = 0; i < 4; ++i) {
                float4 v = src[i];
                int d = d0 + i * 4;
                Lc[d + 0][cr] = v.x;
                Lc[d + 1][cr] = v.y;
                Lc[d + 2][cr] = v.z;
                Lc[d + 3][cr] = v.w;
            }
        }
        __syncthreads();

        // --- 4x4 register-tile GEMM over d ---
        float acc[4][4] = {{0.f}};
#pragma unroll 8
        for (int d = 0; d < EMB; ++d) {
            const float4 xq = *(const float4*)(&Lq[d][ty4]);
            const float4 yc = *(const float4*)(&Lc[d][tx4]);
            float xr[4] = {xq.x, xq.y, xq.z, xq.w};
            float yv[4] = {yc.x, yc.y, yc.z, yc.w};
#pragma unroll
            for (int r = 0; r < 4; ++r)
#pragma unroll
                for (int c = 0; c < 4; ++c)
                    acc[r][c] = fmaf(xr[r], yv[c], acc[r][c]);
        }

        // --- score + running argmin (increasing index order -> strict < keeps first) ---
        const float4 yn4 = *(const float4*)(&ynorm[cbase + tx4]);
        const float ynv[4] = {yn4.x, yn4.y, yn4.z, yn4.w};
#pragma unroll
        for (int r = 0; r < 4; ++r) {
#pragma unroll
            for (int c = 0; c < 4; ++c) {
                float s = fmaf(-2.0f, acc[r][c], ynv[c]);
                if (s < minv[r]) { minv[r] = s; mini[r] = cbase + tx4 + c; }
            }
        }
    }

    // --- cross-thread reduction: 16 tx-threads share each query ---
#pragma unroll
    for (int r = 0; r < 4; ++r) {
        RedV[ty4 + r][tx] = minv[r];
        RedI[ty4 + r][tx] = mini[r];
    }
    __syncthreads();
    if (t < QT) {
        float bv = RedV[t][0];
        int   bi = RedI[t][0];
#pragma unroll
        for (int j = 1; j < 16; ++j) {
            float v = RedV[t][j];
            int   i2 = RedI[t][j];
            if (v < bv || (v == bv && i2 < bi)) { bv = v; bi = i2; }
        }
        int q = qbase + t;
        pval[(size_t)blockIdx.y * NQ + q] = bv;
        pidx[(size_t)blockIdx.y * NQ + q] = bi;
    }
}

// ---------------------------------------------------------------------------
// Kernel 3: combine CSPLIT partials -> final int32 indices
// ---------------------------------------------------------------------------
__global__ void combine_kernel(const float* __restrict__ pval,
                               const int* __restrict__ pidx,
                               int* __restrict__ out)
{
    int q = blockIdx.x * blockDim.x + threadIdx.x;
    if (q >= NQ) return;
    float bv = pval[q];
    int   bi = pidx[q];
#pragma unroll
    for (int s = 1; s < CSPLIT; ++s) {
        float v  = pval[(size_t)s * NQ + q];
        int   i2 = pidx[(size_t)s * NQ + q];
        if (v < bv || (v == bv && i2 < bi)) { bv = v; bi = i2; }
    }
    out[q] = bi;
}

// ---------------------------------------------------------------------------
extern "C" void kernel_launch(void* const* d_in, const int* in_sizes, int n_in,
                              void* d_out, int out_size, void* d_ws, size_t ws_size,
                              hipStream_t stream) {
    const float* X = (const float*)d_in[0];   // [16384, 64]
    const float* W = (const float*)d_in[1];   // [8192, 64]

    float* ynorm = (float*)d_ws;                        // 8192 f
    float* pval  = ynorm + NTOK;                        // CSPLIT*NQ f
    int*   pidx  = (int*)(pval + (size_t)CSPLIT * NQ);  // CSPLIT*NQ i
    int*   out   = (int*)d_out;                         // 16384 i32

    ynorm_kernel<<<NTOK / 256, 256, 0, stream>>>(W, ynorm);
    dim3 grid(NQ / QT, CSPLIT);
    vq_argmin_kernel<<<grid, TPB, 0, stream>>>(X, W, ynorm, pval, pidx);
    combine_kernel<<<NQ / 256, 256, 0, stream>>>(pval, pidx, out);
}